// Round 4
// baseline (716.012 us; speedup 1.0000x reference)
//
#include <hip/hip_runtime.h>
#include <hip/hip_bf16.h>

#define N_ATOMS 100000
#define K_NBR   64
#define N_STRUCT 32
#define HID     128
#define N_EDGE  (N_ATOMS * K_NBR)     // 6,400,000
#define NBLK_E  (N_EDGE / 256)        // 25,000 (exact)

typedef unsigned int uint;

__device__ __forceinline__ uint bf_rne(float f) {        // fp32 -> bf16 bits (RNE)
    uint u = __float_as_uint(f);
    return (u + 0x7fffu + ((u >> 16) & 1u)) >> 16;
}
__device__ __forceinline__ float ubf_lo(uint u) { return __uint_as_float(u << 16); }
__device__ __forceinline__ float ubf_hi(uint u) { return __uint_as_float(u & 0xffff0000u); }

// ---------------------------------------------------------------------------
// Fused compaction (atomic ticket, order-free) + weight prep (block 0).
//   pw4[d] = {W1[0,d], W1[1,d], W1[2,d], w2[d]}
//   gw4[d] = {w2*W1[0,d], w2*W1[1,d], w2*W1[2,d], 0}
// Also zeroes gr8 at masked slots (reference grads are exactly 0 there).
// ---------------------------------------------------------------------------
__global__ __launch_bounds__(256) void compact_kernel(
    const int* __restrict__ mask,
    const float* __restrict__ W1, const float* __restrict__ w2,
    float4* __restrict__ pw4, float4* __restrict__ gw4,
    int* __restrict__ ids, uint2* __restrict__ gr8, int* __restrict__ cnt)
{
    const int tid = threadIdx.x, lane = tid & 63, w = tid >> 6;
    const int ei = blockIdx.x * 256 + tid;
    const int un = (mask[ei] == 0);
    unsigned long long bal = __ballot(un);

    __shared__ int wc[4];
    __shared__ int sbase;
    if (lane == 0) wc[w] = __popcll(bal);

    if (blockIdx.x == 0 && tid < HID) {          // weight prep (no barrier inside)
        float w0 = W1[tid], w1 = W1[HID + tid], wcc = W1[2 * HID + tid];
        float wv = w2[tid];
        pw4[tid] = make_float4(w0, w1, wcc, wv);
        gw4[tid] = make_float4(wv * w0, wv * w1, wv * wcc, 0.f);
    }
    __syncthreads();
    if (tid == 0) sbase = atomicAdd(cnt, wc[0] + wc[1] + wc[2] + wc[3]);
    __syncthreads();

    int base = sbase;
    for (int i = 0; i < w; ++i) base += wc[i];
    int pre = __popcll(bal & ((1ull << lane) - 1ull));
    if (un) ids[base + pre] = ei;
    else    gr8[ei] = make_uint2(0u, 0u);
}

// ---------------------------------------------------------------------------
// Edge MLP over compacted unmasked edges.
// tanh via exact Lambert Pade(5,4): t = p*(945 + u*(105+u)) / (945 + u*(420+15u)),
// u = p^2.  |err| <= ~5e-5 for |p|<=2.2; p clamped to [-4,4] (never hit).
// One v_rcp per 4 hidden units (ganged).  e = sum w2*t; de/dx_c = sum gw*(1-t^2).
// ---------------------------------------------------------------------------
__global__ __launch_bounds__(256) void edge_mlp(
    const float* __restrict__ x, const int* __restrict__ ids,
    const int* __restrict__ cntp, const int* __restrict__ batch,
    const float4* __restrict__ pw4, const float4* __restrict__ gw4,
    uint2* __restrict__ gr8, float* __restrict__ part)
{
    __shared__ float sp[N_STRUCT];
    int tid = threadIdx.x;
    if (tid < N_STRUCT) sp[tid] = 0.f;
    __syncthreads();

    int i = blockIdx.x * 256 + tid;
    int cnt = cntp[0];
    if (i < cnt) {
        int eid = ids[i];
        const float* xp = x + (size_t)eid * 3;
        float x0 = xp[0], x1 = xp[1], x2 = xp[2];
        float esum = 0.f, g0 = 0.f, g1 = 0.f, g2 = 0.f;
        for (int d = 0; d < HID; d += 4) {
            float4 wa = pw4[d], wb = pw4[d + 1], wc = pw4[d + 2], wd = pw4[d + 3];
            float4 Ga = gw4[d], Gb = gw4[d + 1], Gc = gw4[d + 2], Gd = gw4[d + 3];

            float pa = fmaf(x0, wa.x, fmaf(x1, wa.y, x2 * wa.z));
            float pb = fmaf(x0, wb.x, fmaf(x1, wb.y, x2 * wb.z));
            float pc = fmaf(x0, wc.x, fmaf(x1, wc.y, x2 * wc.z));
            float pd = fmaf(x0, wd.x, fmaf(x1, wd.y, x2 * wd.z));
            pa = fminf(4.f, fmaxf(-4.f, pa));
            pb = fminf(4.f, fmaxf(-4.f, pb));
            pc = fminf(4.f, fmaxf(-4.f, pc));
            pd = fminf(4.f, fmaxf(-4.f, pd));

            float ua = pa * pa, ub = pb * pb, uc = pc * pc, ud = pd * pd;
            float na = pa * fmaf(ua, ua + 105.f, 945.f);      // p*(945+u*(105+u))
            float nb = pb * fmaf(ub, ub + 105.f, 945.f);
            float nc = pc * fmaf(uc, uc + 105.f, 945.f);
            float nd = pd * fmaf(ud, ud + 105.f, 945.f);
            float Da = fmaf(ua, fmaf(ua, 15.f, 420.f), 945.f); // 945+u*(420+15u)
            float Db = fmaf(ub, fmaf(ub, 15.f, 420.f), 945.f);
            float Dc = fmaf(uc, fmaf(uc, 15.f, 420.f), 945.f);
            float Dd = fmaf(ud, fmaf(ud, 15.f, 420.f), 945.f);

            float Pab = Da * Db, Pcd = Dc * Dd;
            float q   = __builtin_amdgcn_rcpf(Pab * Pcd);     // one rcp per 4 d
            float qab = q * Pcd, qcd = q * Pab;
            float ta = na * (qab * Db);
            float tb = nb * (qab * Da);
            float tc = nc * (qcd * Dd);
            float td = nd * (qcd * Dc);

            esum = fmaf(wa.w, ta, esum);
            esum = fmaf(wb.w, tb, esum);
            esum = fmaf(wc.w, tc, esum);
            esum = fmaf(wd.w, td, esum);
            float sa = fmaf(-ta, ta, 1.f);                    // 1 - t^2
            float sb = fmaf(-tb, tb, 1.f);
            float sc = fmaf(-tc, tc, 1.f);
            float sd = fmaf(-td, td, 1.f);
            g0 = fmaf(sa, Ga.x, g0); g1 = fmaf(sa, Ga.y, g1); g2 = fmaf(sa, Ga.z, g2);
            g0 = fmaf(sb, Gb.x, g0); g1 = fmaf(sb, Gb.y, g1); g2 = fmaf(sb, Gb.z, g2);
            g0 = fmaf(sc, Gc.x, g0); g1 = fmaf(sc, Gc.y, g1); g2 = fmaf(sc, Gc.z, g2);
            g0 = fmaf(sd, Gd.x, g0); g1 = fmaf(sd, Gd.y, g1); g2 = fmaf(sd, Gd.z, g2);
        }
        uint lo = bf_rne(g0) | (bf_rne(g1) << 16);
        uint hi = bf_rne(g2);
        gr8[eid] = make_uint2(lo, hi);
        atomicAdd(&sp[batch[eid >> 6]], esum);
    }
    __syncthreads();
    if (tid < N_STRUCT) part[(size_t)tid * NBLK_E + blockIdx.x] = sp[tid];
}

// ---------------------------------------------------------------------------
// Transpose nidx [K,N] and fuse with pos/mask -> gidx[n,k] = m ? -1 : nb*64+ps
// (gidx aliases ids; runs AFTER edge_mlp)
// ---------------------------------------------------------------------------
__global__ __launch_bounds__(256) void transpose_gidx(
    const int* __restrict__ src, const int* __restrict__ pos,
    const int* __restrict__ mask, int* __restrict__ gidx)
{
    __shared__ int tile[64][65];
    const int n0 = blockIdx.x * 64;
    const int lane = threadIdx.x & 63;
    const int ty = threadIdx.x >> 6;
    #pragma unroll
    for (int i = 0; i < 16; ++i) {
        int k = i * 4 + ty, n = n0 + lane;
        tile[k][lane] = (n < N_ATOMS) ? src[k * N_ATOMS + n] : 0;
    }
    __syncthreads();
    #pragma unroll
    for (int i = 0; i < 16; ++i) {
        int nl = i * 4 + ty, n = n0 + nl;
        if (n < N_ATOMS) {
            int ei = n * 64 + lane;
            int nb = tile[lane][nl];
            gidx[ei] = (mask[ei] != 0) ? -1 : (nb * 64 + pos[ei]);
        }
    }
}

// ---------------------------------------------------------------------------
// Forces (2 atoms per wave) + preds reduce in blocks 0..31
// ---------------------------------------------------------------------------
__global__ __launch_bounds__(256) void atom_kernel(
    const uint2* __restrict__ gr8, const int* __restrict__ gidx,
    const float* __restrict__ part, float* __restrict__ out)
{
    int tid = threadIdx.x, lane = tid & 63, w = tid >> 6;
    int nA = blockIdx.x * 8 + w * 2;
    int eiA = nA * 64 + lane;
    int eiB = eiA + 64;

    int gA = gidx[eiA], gB = gidx[eiB];
    uint2 aA = gr8[eiA], aB = gr8[eiB];       // coalesced; masked entries are 0
    uint2 bA = make_uint2(0u, 0u), bB = make_uint2(0u, 0u);
    if (gA >= 0) bA = gr8[gA];                // aligned 8B random gather
    if (gB >= 0) bB = gr8[gB];

    float fA0 = ubf_lo(aA.x) - ubf_lo(bA.x);
    float fA1 = ubf_hi(aA.x) - ubf_hi(bA.x);
    float fA2 = ubf_lo(aA.y) - ubf_lo(bA.y);
    float fB0 = ubf_lo(aB.x) - ubf_lo(bB.x);
    float fB1 = ubf_hi(aB.x) - ubf_hi(bB.x);
    float fB2 = ubf_lo(aB.y) - ubf_lo(bB.y);

    for (int off = 32; off; off >>= 1) {
        fA0 += __shfl_down(fA0, off, 64);
        fA1 += __shfl_down(fA1, off, 64);
        fA2 += __shfl_down(fA2, off, 64);
        fB0 += __shfl_down(fB0, off, 64);
        fB1 += __shfl_down(fB1, off, 64);
        fB2 += __shfl_down(fB2, off, 64);
    }
    if (lane == 0) {
        float* fo = out + N_STRUCT + (size_t)nA * 3;
        fo[0] = fA0; fo[1] = fA1; fo[2] = fA2;
        fo[3] = fB0; fo[4] = fB1; fo[5] = fB2;
    }

    if (blockIdx.x < N_STRUCT) {
        int s = blockIdx.x;
        float v = 0.f;
        for (int i = tid; i < NBLK_E; i += 256) v += part[(size_t)s * NBLK_E + i];
        for (int off = 32; off; off >>= 1) v += __shfl_down(v, off, 64);
        __shared__ float sv[4];
        if (lane == 0) sv[w] = v;
        __syncthreads();
        if (tid == 0) out[s] = sv[0] + sv[1] + sv[2] + sv[3];
    }
}

// ---------------------------------------------------------------------------
extern "C" void kernel_launch(void* const* d_in, const int* in_sizes, int n_in,
                              void* d_out, int out_size, void* d_ws, size_t ws_size,
                              hipStream_t stream)
{
    const float* x    = (const float*)d_in[0];
    const int*   nidx = (const int*)d_in[1];   // [K, N]
    const int*   npos = (const int*)d_in[2];   // [N, K]
    const int*   mask = (const int*)d_in[3];   // [N, K]
    const int*   bidx = (const int*)d_in[4];   // [N]
    const float* W1   = (const float*)d_in[5]; // [3, HID]
    const float* w2   = (const float*)d_in[6]; // [HID]
    float* out = (float*)d_out;

    char* ws = (char*)d_ws;
    uint2* gr8  = (uint2*)ws;                                  // 51.2 MB
    int*   ids  = (int*)(ws + (size_t)N_EDGE * 8);             // 25.6 MB (aliased by gidx)
    int*   gidx = ids;
    float* part = (float*)(ws + (size_t)N_EDGE * 8 + (size_t)N_EDGE * 4);   // 3.2 MB
    char*  tail = ws + (size_t)N_EDGE * 8 + (size_t)N_EDGE * 4
                     + (size_t)N_STRUCT * NBLK_E * 4;
    float4* pw4   = (float4*)tail;                             // 2 KB
    float4* gw4   = (float4*)(tail + HID * 16);                // 2 KB
    int*    cnt   = (int*)(tail + 2 * HID * 16);

    hipMemsetAsync(cnt, 0, sizeof(int), stream);
    hipLaunchKernelGGL(compact_kernel, dim3(NBLK_E), dim3(256), 0, stream,
                       mask, W1, w2, pw4, gw4, ids, gr8, cnt);
    hipLaunchKernelGGL(edge_mlp, dim3(NBLK_E), dim3(256), 0, stream,
                       x, ids, cnt, bidx, pw4, gw4, gr8, part);
    hipLaunchKernelGGL(transpose_gidx, dim3((N_ATOMS + 63) / 64), dim3(256),
                       0, stream, nidx, npos, mask, gidx);     // after edge_mlp: alias safe
    hipLaunchKernelGGL(atom_kernel, dim3(N_ATOMS / 8), dim3(256), 0, stream,
                       gr8, gidx, part, out);
}

// Round 5
// 492.986 us; speedup vs baseline: 1.4524x; 1.4524x over previous
//
#include <hip/hip_runtime.h>
#include <hip/hip_bf16.h>

#define N_ATOMS 100000
#define K_NBR   64
#define N_STRUCT 32
#define HID     128
#define N_EDGE  (N_ATOMS * K_NBR)     // 6,400,000
#define NBLK_E  (N_EDGE / 256)        // 25,000 (exact)
#define NBLK_A  ((N_ATOMS + 63) / 64) // 1563

typedef unsigned int uint;

__device__ __forceinline__ uint bf_rne(float f) {        // fp32 -> bf16 bits (RNE)
    uint u = __float_as_uint(f);
    return (u + 0x7fffu + ((u >> 16) & 1u)) >> 16;
}
__device__ __forceinline__ float ubf_lo(uint u) { return __uint_as_float(u << 16); }
__device__ __forceinline__ float ubf_hi(uint u) { return __uint_as_float(u & 0xffff0000u); }

// ---------------------------------------------------------------------------
// count (per-block unmasked count) + weight prep in block 0.
//   pw4[d] = {W1[0,d], W1[1,d], W1[2,d], w2[d]}
//   gw4[d] = {w2*W1[0,d], w2*W1[1,d], w2*W1[2,d], 0}
// ---------------------------------------------------------------------------
__global__ __launch_bounds__(256) void count_prep(
    const int* __restrict__ mask, int* __restrict__ bc,
    const float* __restrict__ W1, const float* __restrict__ w2,
    float4* __restrict__ pw4, float4* __restrict__ gw4)
{
    const int tid = threadIdx.x;
    int ei = blockIdx.x * 256 + tid;
    unsigned long long bal = __ballot(mask[ei] == 0);
    __shared__ int c[4];
    if ((tid & 63) == 0) c[tid >> 6] = __popcll(bal);

    if (blockIdx.x == 0 && tid < HID) {
        float w0 = W1[tid], w1 = W1[HID + tid], wcc = W1[2 * HID + tid];
        float wv = w2[tid];
        pw4[tid] = make_float4(w0, w1, wcc, wv);
        gw4[tid] = make_float4(wv * w0, wv * w1, wv * wcc, 0.f);
    }
    __syncthreads();
    if (tid == 0) bc[blockIdx.x] = c[0] + c[1] + c[2] + c[3];
}

// ---------------------------------------------------------------------------
// Single-block exclusive scan of 25,000 block counts (deterministic).
// ---------------------------------------------------------------------------
__global__ void scan_kernel(const int* __restrict__ bc, int* __restrict__ bb,
                            int* __restrict__ cnt)
{
    __shared__ int ps[256];
    const int CH = (NBLK_E + 255) / 256;         // 98
    int tid = threadIdx.x;
    int s = 0;
    for (int j = 0; j < CH; ++j) {
        int idx = tid * CH + j;
        if (idx < NBLK_E) s += bc[idx];
    }
    ps[tid] = s;
    __syncthreads();
    if (tid == 0) {
        int acc = 0;
        for (int i = 0; i < 256; ++i) { int v = ps[i]; ps[i] = acc; acc += v; }
        cnt[0] = acc;
    }
    __syncthreads();
    int base = ps[tid];
    for (int j = 0; j < CH; ++j) {
        int idx = tid * CH + j;
        if (idx < NBLK_E) { bb[idx] = base; base += bc[idx]; }
    }
}

// scatter compacted ids AND zero gr8 at masked slots (gathered sources must
// read 0 there; ws is poisoned 0xAA before every launch)
__global__ __launch_bounds__(256) void scatter_zero(
    const int* __restrict__ mask, const int* __restrict__ bb,
    int* __restrict__ ids, uint2* __restrict__ gr8)
{
    int tid = threadIdx.x, lane = tid & 63, w = tid >> 6;
    int ei = blockIdx.x * 256 + tid;
    int un = (mask[ei] == 0);
    unsigned long long bal = __ballot(un);
    __shared__ int woff[4];
    if (lane == 0) woff[w] = __popcll(bal);
    __syncthreads();
    int base = bb[blockIdx.x];
    for (int i = 0; i < w; ++i) base += woff[i];
    int pre = __popcll(bal & ((1ull << lane) - 1ull));
    if (un) ids[base + pre] = ei;
    else    gr8[ei] = make_uint2(0u, 0u);
}

// ---------------------------------------------------------------------------
// Edge MLP over compacted unmasked edges.
// tanh via exact Lambert Pade(5,4): t = p*(945 + u*(105+u)) / (945 + u*(420+15u)),
// u = p^2; one v_rcp per 4 hidden units (ganged).
// ---------------------------------------------------------------------------
__global__ __launch_bounds__(256) void edge_mlp(
    const float* __restrict__ x, const int* __restrict__ ids,
    const int* __restrict__ cntp, const int* __restrict__ batch,
    const float4* __restrict__ pw4, const float4* __restrict__ gw4,
    uint2* __restrict__ gr8, float* __restrict__ part)
{
    __shared__ float sp[N_STRUCT];
    int tid = threadIdx.x;
    if (tid < N_STRUCT) sp[tid] = 0.f;
    __syncthreads();

    int i = blockIdx.x * 256 + tid;
    int cnt = cntp[0];
    if (i < cnt) {
        int eid = ids[i];
        const float* xp = x + (size_t)eid * 3;
        float x0 = xp[0], x1 = xp[1], x2 = xp[2];
        float esum = 0.f, g0 = 0.f, g1 = 0.f, g2 = 0.f;
        for (int d = 0; d < HID; d += 4) {
            float4 wa = pw4[d], wb = pw4[d + 1], wc = pw4[d + 2], wd = pw4[d + 3];
            float4 Ga = gw4[d], Gb = gw4[d + 1], Gc = gw4[d + 2], Gd = gw4[d + 3];

            float pa = fmaf(x0, wa.x, fmaf(x1, wa.y, x2 * wa.z));
            float pb = fmaf(x0, wb.x, fmaf(x1, wb.y, x2 * wb.z));
            float pc = fmaf(x0, wc.x, fmaf(x1, wc.y, x2 * wc.z));
            float pd = fmaf(x0, wd.x, fmaf(x1, wd.y, x2 * wd.z));
            pa = fminf(4.f, fmaxf(-4.f, pa));
            pb = fminf(4.f, fmaxf(-4.f, pb));
            pc = fminf(4.f, fmaxf(-4.f, pc));
            pd = fminf(4.f, fmaxf(-4.f, pd));

            float ua = pa * pa, ub = pb * pb, uc = pc * pc, ud = pd * pd;
            float na = pa * fmaf(ua, ua + 105.f, 945.f);
            float nb = pb * fmaf(ub, ub + 105.f, 945.f);
            float nc = pc * fmaf(uc, uc + 105.f, 945.f);
            float nd = pd * fmaf(ud, ud + 105.f, 945.f);
            float Da = fmaf(ua, fmaf(ua, 15.f, 420.f), 945.f);
            float Db = fmaf(ub, fmaf(ub, 15.f, 420.f), 945.f);
            float Dc = fmaf(uc, fmaf(uc, 15.f, 420.f), 945.f);
            float Dd = fmaf(ud, fmaf(ud, 15.f, 420.f), 945.f);

            float Pab = Da * Db, Pcd = Dc * Dd;
            float q   = __builtin_amdgcn_rcpf(Pab * Pcd);     // one rcp per 4 d
            float qab = q * Pcd, qcd = q * Pab;
            float ta = na * (qab * Db);
            float tb = nb * (qab * Da);
            float tc = nc * (qcd * Dd);
            float td = nd * (qcd * Dc);

            esum = fmaf(wa.w, ta, esum);
            esum = fmaf(wb.w, tb, esum);
            esum = fmaf(wc.w, tc, esum);
            esum = fmaf(wd.w, td, esum);
            float sa = fmaf(-ta, ta, 1.f);
            float sb = fmaf(-tb, tb, 1.f);
            float sc = fmaf(-tc, tc, 1.f);
            float sd = fmaf(-td, td, 1.f);
            g0 = fmaf(sa, Ga.x, g0); g1 = fmaf(sa, Ga.y, g1); g2 = fmaf(sa, Ga.z, g2);
            g0 = fmaf(sb, Gb.x, g0); g1 = fmaf(sb, Gb.y, g1); g2 = fmaf(sb, Gb.z, g2);
            g0 = fmaf(sc, Gc.x, g0); g1 = fmaf(sc, Gc.y, g1); g2 = fmaf(sc, Gc.z, g2);
            g0 = fmaf(sd, Gd.x, g0); g1 = fmaf(sd, Gd.y, g1); g2 = fmaf(sd, Gd.z, g2);
        }
        uint lo = bf_rne(g0) | (bf_rne(g1) << 16);
        uint hi = bf_rne(g2);
        gr8[eid] = make_uint2(lo, hi);
        atomicAdd(&sp[batch[eid >> 6]], esum);
    }
    __syncthreads();
    if (tid < N_STRUCT) part[(size_t)tid * NBLK_E + blockIdx.x] = sp[tid];
}

// ---------------------------------------------------------------------------
// Fused forces: block owns 64 atoms. Phase A transposes its 64x64 nidx tile
// in LDS (coalesced [K,N] reads); Phase B computes forces (wave = 2 atoms per
// iteration, 8 iterations). Blocks 0..31 also reduce preds partials.
// ---------------------------------------------------------------------------
__global__ __launch_bounds__(256) void atom_fused(
    const uint2* __restrict__ gr8, const int* __restrict__ nidx,
    const int* __restrict__ pos, const int* __restrict__ mask,
    const float* __restrict__ part, float* __restrict__ out)
{
    __shared__ int tile[64][65];
    __shared__ float sv[4];
    const int tid = threadIdx.x, lane = tid & 63, w = tid >> 6;
    const int n0 = blockIdx.x * 64;

    #pragma unroll
    for (int i = 0; i < 16; ++i) {                 // coalesced read of nidx[K,N]
        int k = i * 4 + w, n = n0 + lane;
        tile[k][lane] = (n < N_ATOMS) ? nidx[k * N_ATOMS + n] : 0;
    }
    __syncthreads();

    #pragma unroll 2
    for (int j = 0; j < 8; ++j) {                  // wave: atoms nA, nA+1
        int nlA = w * 16 + 2 * j;
        int nA  = n0 + nlA;
        int nB  = nA + 1;
        bool vA = (nA < N_ATOMS), vB = (nB < N_ATOMS);

        float fA0 = 0.f, fA1 = 0.f, fA2 = 0.f, fB0 = 0.f, fB1 = 0.f, fB2 = 0.f;
        if (vA) {
            int eiA = nA * 64 + lane;
            int mA = mask[eiA], psA = pos[eiA];
            int nbA = tile[lane][nlA];             // (lane+nlA)%32 banks: 2-way, free
            uint2 aA = gr8[eiA];                   // coalesced; masked slots are 0
            uint2 bA = make_uint2(0u, 0u);
            if (!mA) bA = gr8[(size_t)nbA * 64 + psA];   // aligned 8B gather
            fA0 = ubf_lo(aA.x) - ubf_lo(bA.x);
            fA1 = ubf_hi(aA.x) - ubf_hi(bA.x);
            fA2 = ubf_lo(aA.y) - ubf_lo(bA.y);
        }
        if (vB) {
            int eiB = nB * 64 + lane;
            int mB = mask[eiB], psB = pos[eiB];
            int nbB = tile[lane][nlA + 1];
            uint2 aB = gr8[eiB];
            uint2 bB = make_uint2(0u, 0u);
            if (!mB) bB = gr8[(size_t)nbB * 64 + psB];
            fB0 = ubf_lo(aB.x) - ubf_lo(bB.x);
            fB1 = ubf_hi(aB.x) - ubf_hi(bB.x);
            fB2 = ubf_lo(aB.y) - ubf_lo(bB.y);
        }

        for (int off = 32; off; off >>= 1) {
            fA0 += __shfl_down(fA0, off, 64);
            fA1 += __shfl_down(fA1, off, 64);
            fA2 += __shfl_down(fA2, off, 64);
            fB0 += __shfl_down(fB0, off, 64);
            fB1 += __shfl_down(fB1, off, 64);
            fB2 += __shfl_down(fB2, off, 64);
        }
        if (lane == 0 && vA) {
            float* fo = out + N_STRUCT + (size_t)nA * 3;
            fo[0] = fA0; fo[1] = fA1; fo[2] = fA2;
            if (vB) { fo[3] = fB0; fo[4] = fB1; fo[5] = fB2; }
        }
    }

    if (blockIdx.x < N_STRUCT) {                   // fused preds reduction
        int s = blockIdx.x;
        float v = 0.f;
        for (int i = tid; i < NBLK_E; i += 256) v += part[(size_t)s * NBLK_E + i];
        for (int off = 32; off; off >>= 1) v += __shfl_down(v, off, 64);
        if (lane == 0) sv[w] = v;
        __syncthreads();
        if (tid == 0) out[s] = sv[0] + sv[1] + sv[2] + sv[3];
    }
}

// ---------------------------------------------------------------------------
extern "C" void kernel_launch(void* const* d_in, const int* in_sizes, int n_in,
                              void* d_out, int out_size, void* d_ws, size_t ws_size,
                              hipStream_t stream)
{
    const float* x    = (const float*)d_in[0];
    const int*   nidx = (const int*)d_in[1];   // [K, N]
    const int*   npos = (const int*)d_in[2];   // [N, K]
    const int*   mask = (const int*)d_in[3];   // [N, K]
    const int*   bidx = (const int*)d_in[4];   // [N]
    const float* W1   = (const float*)d_in[5]; // [3, HID]
    const float* w2   = (const float*)d_in[6]; // [HID]
    float* out = (float*)d_out;

    char* ws = (char*)d_ws;
    uint2* gr8  = (uint2*)ws;                                  // 51.2 MB
    int*   ids  = (int*)(ws + (size_t)N_EDGE * 8);             // 25.6 MB (worst case)
    float* part = (float*)(ws + (size_t)N_EDGE * 8 + (size_t)N_EDGE * 4);   // 3.2 MB
    char*  tail = ws + (size_t)N_EDGE * 8 + (size_t)N_EDGE * 4
                     + (size_t)N_STRUCT * NBLK_E * 4;
    int*    bc    = (int*)tail;                                // 100 KB
    int*    bb    = (int*)(tail + NBLK_E * 4);                 // 100 KB
    float4* pw4   = (float4*)(tail + 2 * NBLK_E * 4);          // 2 KB
    float4* gw4   = (float4*)(tail + 2 * NBLK_E * 4 + HID * 16);
    int*    cnt   = (int*)(tail + 2 * NBLK_E * 4 + 2 * HID * 16);

    hipLaunchKernelGGL(count_prep, dim3(NBLK_E), dim3(256), 0, stream,
                       mask, bc, W1, w2, pw4, gw4);
    hipLaunchKernelGGL(scan_kernel, dim3(1), dim3(256), 0, stream, bc, bb, cnt);
    hipLaunchKernelGGL(scatter_zero, dim3(NBLK_E), dim3(256), 0, stream,
                       mask, bb, ids, gr8);
    hipLaunchKernelGGL(edge_mlp, dim3(NBLK_E), dim3(256), 0, stream,
                       x, ids, cnt, bidx, pw4, gw4, gr8, part);
    hipLaunchKernelGGL(atom_fused, dim3(NBLK_A), dim3(256), 0, stream,
                       gr8, nidx, npos, mask, part, out);
}

// Round 6
// 383.662 us; speedup vs baseline: 1.8663x; 1.2849x over previous
//
#include <hip/hip_runtime.h>
#include <hip/hip_bf16.h>

#define N_ATOMS 100000
#define K_NBR   64
#define N_STRUCT 32
#define HID     128
#define N_EDGE  (N_ATOMS * K_NBR)       // 6,400,000
#define ATOMS_PB 32                     // atoms per edge block
#define EDGES_PB (ATOMS_PB * K_NBR)     // 2048
#define NBLK_EL (N_ATOMS / ATOMS_PB)    // 3125 (exact)
#define NBLK_A  ((N_ATOMS + 63) / 64)   // 1563

typedef unsigned int uint;

#if __has_builtin(__builtin_amdgcn_exp2f)
#define EXP2(v) __builtin_amdgcn_exp2f(v)
#else
#define EXP2(v) __expf((v) * 0.69314718056f)
#endif

__device__ __forceinline__ uint bf_rne(float f) {        // fp32 -> bf16 bits (RNE)
    uint u = __float_as_uint(f);
    return (u + 0x7fffu + ((u >> 16) & 1u)) >> 16;
}
__device__ __forceinline__ float ubf_lo(uint u) { return __uint_as_float(u << 16); }
__device__ __forceinline__ float ubf_hi(uint u) { return __uint_as_float(u & 0xffff0000u); }

// ---------------------------------------------------------------------------
// Weight prep (1 block):
//   pw4[d] = {2log2e*W1[0,d], 2log2e*W1[1,d], 2log2e*W1[2,d], w2[d]}
//   gw4[d] = {4*w2*W1[0,d],   4*w2*W1[1,d],   4*w2*W1[2,d],   0}
// identities: ex = e^{2p} = exp2(x·pw); r = 1/(1+ex); t = 1-2r;
//             e = sum w2 t = sumw2 - 2 sum w2 r; (1-t^2)/4 = r - r^2.
// ---------------------------------------------------------------------------
__global__ void prep_kernel(const float* __restrict__ W1, const float* __restrict__ w2,
                            float4* __restrict__ pw4, float4* __restrict__ gw4,
                            float* __restrict__ sumw2)
{
    const float L2E2 = 2.885390082f;     // 2*log2(e)
    int d = threadIdx.x;                 // 128 threads
    float w0 = W1[d], w1 = W1[HID + d], wc = W1[2 * HID + d], wv = w2[d];
    pw4[d] = make_float4(L2E2 * w0, L2E2 * w1, L2E2 * wc, wv);
    gw4[d] = make_float4(4.f * wv * w0, 4.f * wv * w1, 4.f * wv * wc, 0.f);
    float v = wv;
    for (int off = 32; off; off >>= 1) v += __shfl_down(v, off, 64);
    __shared__ float sw_[2];
    if ((threadIdx.x & 63) == 0) sw_[threadIdx.x >> 6] = v;
    __syncthreads();
    if (threadIdx.x == 0) sumw2[0] = sw_[0] + sw_[1];
}

// ---------------------------------------------------------------------------
// Edge MLP with block-local compaction: block owns 32 atoms (2048 edges).
// Phase A: compact unmasked local edge ids into LDS (ballot + LDS ticket),
//          zero gr8 at masked slots.
// Phase B: dense MLP loop over the ~1024-entry list (exp-based tanh,
//          4-way-ganged v_rcp, weights via wave-uniform s_loads).
// ---------------------------------------------------------------------------
__global__ __launch_bounds__(256) void edge_local(
    const float* __restrict__ x, const int* __restrict__ mask,
    const int* __restrict__ batch,
    const float4* __restrict__ pw4, const float4* __restrict__ gw4,
    const float* __restrict__ sumw2p,
    uint2* __restrict__ gr8, float* __restrict__ part)
{
    __shared__ unsigned short list[EDGES_PB];
    __shared__ int   lcnt;
    __shared__ float sp[N_STRUCT];
    __shared__ int   sbatch[ATOMS_PB];

    const int tid = threadIdx.x, lane = tid & 63;
    const int ebase = blockIdx.x * EDGES_PB;

    if (tid == 0) lcnt = 0;
    if (tid < N_STRUCT) sp[tid] = 0.f;
    if (tid < ATOMS_PB) sbatch[tid] = batch[blockIdx.x * ATOMS_PB + tid];
    __syncthreads();

    #pragma unroll
    for (int p = 0; p < EDGES_PB / 256; ++p) {           // 8 passes, coalesced
        int le = p * 256 + tid;
        int m = mask[ebase + le];
        unsigned long long bal = __ballot(m == 0);
        int wcnt = __popcll(bal);
        int pre  = __popcll(bal & ((1ull << lane) - 1ull));
        int wbase;
        if (lane == 0) wbase = atomicAdd(&lcnt, wcnt);   // block-local ticket
        wbase = __shfl(wbase, 0, 64);
        if (m == 0) list[wbase + pre] = (unsigned short)le;
        else        gr8[ebase + le] = make_uint2(0u, 0u);
    }
    __syncthreads();

    const int L = lcnt;
    const float sumw2 = sumw2p[0];

    for (int i = tid; i < L; i += 256) {
        int le  = list[i];
        int eid = ebase + le;
        const float* xp = x + (size_t)eid * 3;
        float x0 = xp[0], x1 = xp[1], x2 = xp[2];
        float rsum = 0.f, g0 = 0.f, g1 = 0.f, g2 = 0.f;
        for (int d = 0; d < HID; d += 4) {
            float4 wa = pw4[d], wb = pw4[d + 1], wc = pw4[d + 2], wd = pw4[d + 3];
            float4 Ga = gw4[d], Gb = gw4[d + 1], Gc = gw4[d + 2], Gd = gw4[d + 3];
            float ea = EXP2(fmaf(x0, wa.x, fmaf(x1, wa.y, x2 * wa.z)));
            float eb = EXP2(fmaf(x0, wb.x, fmaf(x1, wb.y, x2 * wb.z)));
            float ec = EXP2(fmaf(x0, wc.x, fmaf(x1, wc.y, x2 * wc.z)));
            float ed = EXP2(fmaf(x0, wd.x, fmaf(x1, wd.y, x2 * wd.z)));
            float aa = ea + 1.f, ab = eb + 1.f, ac = ec + 1.f, ad = ed + 1.f;
            float pab = aa * ab, pcd = ac * ad;
            float q   = __builtin_amdgcn_rcpf(pab * pcd);     // one rcp per 4 d
            float qab = q * pcd, qcd = q * pab;
            float ra = qab * ab, rb = qab * aa, rc = qcd * ad, rd = qcd * ac;
            rsum = fmaf(wa.w, ra, rsum);
            rsum = fmaf(wb.w, rb, rsum);
            rsum = fmaf(wc.w, rc, rsum);
            rsum = fmaf(wd.w, rd, rsum);
            float sa = fmaf(-ra, ra, ra);                     // r-r^2 = (1-t^2)/4
            float sb = fmaf(-rb, rb, rb);
            float sc = fmaf(-rc, rc, rc);
            float sd = fmaf(-rd, rd, rd);
            g0 = fmaf(sa, Ga.x, g0); g1 = fmaf(sa, Ga.y, g1); g2 = fmaf(sa, Ga.z, g2);
            g0 = fmaf(sb, Gb.x, g0); g1 = fmaf(sb, Gb.y, g1); g2 = fmaf(sb, Gb.z, g2);
            g0 = fmaf(sc, Gc.x, g0); g1 = fmaf(sc, Gc.y, g1); g2 = fmaf(sc, Gc.z, g2);
            g0 = fmaf(sd, Gd.x, g0); g1 = fmaf(sd, Gd.y, g1); g2 = fmaf(sd, Gd.z, g2);
        }
        float e = fmaf(-2.f, rsum, sumw2);
        uint lo = bf_rne(g0) | (bf_rne(g1) << 16);
        uint hi = bf_rne(g2);
        gr8[eid] = make_uint2(lo, hi);
        atomicAdd(&sp[sbatch[le >> 6]], e);
    }
    __syncthreads();
    if (tid < N_STRUCT) part[(size_t)tid * NBLK_EL + blockIdx.x] = sp[tid];
}

// ---------------------------------------------------------------------------
// Fused forces: block owns 64 atoms; LDS-transposes its 64x64 nidx tile
// (coalesced [K,N] reads), then wave = 2 atoms/iter. Blocks 0..31 also
// reduce the preds partials.
// ---------------------------------------------------------------------------
__global__ __launch_bounds__(256) void atom_fused(
    const uint2* __restrict__ gr8, const int* __restrict__ nidx,
    const int* __restrict__ pos, const int* __restrict__ mask,
    const float* __restrict__ part, float* __restrict__ out)
{
    __shared__ int tile[64][65];
    __shared__ float sv[4];
    const int tid = threadIdx.x, lane = tid & 63, w = tid >> 6;
    const int n0 = blockIdx.x * 64;

    #pragma unroll
    for (int i = 0; i < 16; ++i) {                 // coalesced read of nidx[K,N]
        int k = i * 4 + w, n = n0 + lane;
        tile[k][lane] = (n < N_ATOMS) ? nidx[k * N_ATOMS + n] : 0;
    }
    __syncthreads();

    #pragma unroll 2
    for (int j = 0; j < 8; ++j) {                  // wave: atoms nA, nA+1
        int nlA = w * 16 + 2 * j;
        int nA  = n0 + nlA;
        int nB  = nA + 1;
        bool vA = (nA < N_ATOMS), vB = (nB < N_ATOMS);

        float fA0 = 0.f, fA1 = 0.f, fA2 = 0.f, fB0 = 0.f, fB1 = 0.f, fB2 = 0.f;
        if (vA) {
            int eiA = nA * 64 + lane;
            int mA = mask[eiA], psA = pos[eiA];
            int nbA = tile[lane][nlA];
            uint2 aA = gr8[eiA];                   // coalesced; masked slots are 0
            uint2 bA = make_uint2(0u, 0u);
            if (!mA) bA = gr8[(size_t)nbA * 64 + psA];   // aligned 8B gather
            fA0 = ubf_lo(aA.x) - ubf_lo(bA.x);
            fA1 = ubf_hi(aA.x) - ubf_hi(bA.x);
            fA2 = ubf_lo(aA.y) - ubf_lo(bA.y);
        }
        if (vB) {
            int eiB = nB * 64 + lane;
            int mB = mask[eiB], psB = pos[eiB];
            int nbB = tile[lane][nlA + 1];
            uint2 aB = gr8[eiB];
            uint2 bB = make_uint2(0u, 0u);
            if (!mB) bB = gr8[(size_t)nbB * 64 + psB];
            fB0 = ubf_lo(aB.x) - ubf_lo(bB.x);
            fB1 = ubf_hi(aB.x) - ubf_hi(bB.x);
            fB2 = ubf_lo(aB.y) - ubf_lo(bB.y);
        }

        for (int off = 32; off; off >>= 1) {
            fA0 += __shfl_down(fA0, off, 64);
            fA1 += __shfl_down(fA1, off, 64);
            fA2 += __shfl_down(fA2, off, 64);
            fB0 += __shfl_down(fB0, off, 64);
            fB1 += __shfl_down(fB1, off, 64);
            fB2 += __shfl_down(fB2, off, 64);
        }
        if (lane == 0 && vA) {
            float* fo = out + N_STRUCT + (size_t)nA * 3;
            fo[0] = fA0; fo[1] = fA1; fo[2] = fA2;
            if (vB) { fo[3] = fB0; fo[4] = fB1; fo[5] = fB2; }
        }
    }

    if (blockIdx.x < N_STRUCT) {                   // fused preds reduction
        int s = blockIdx.x;
        float v = 0.f;
        for (int i = tid; i < NBLK_EL; i += 256) v += part[(size_t)s * NBLK_EL + i];
        for (int off = 32; off; off >>= 1) v += __shfl_down(v, off, 64);
        if (lane == 0) sv[w] = v;
        __syncthreads();
        if (tid == 0) out[s] = sv[0] + sv[1] + sv[2] + sv[3];
    }
}

// ---------------------------------------------------------------------------
extern "C" void kernel_launch(void* const* d_in, const int* in_sizes, int n_in,
                              void* d_out, int out_size, void* d_ws, size_t ws_size,
                              hipStream_t stream)
{
    const float* x    = (const float*)d_in[0];
    const int*   nidx = (const int*)d_in[1];   // [K, N]
    const int*   npos = (const int*)d_in[2];   // [N, K]
    const int*   mask = (const int*)d_in[3];   // [N, K]
    const int*   bidx = (const int*)d_in[4];   // [N]
    const float* W1   = (const float*)d_in[5]; // [3, HID]
    const float* w2   = (const float*)d_in[6]; // [HID]
    float* out = (float*)d_out;

    char* ws = (char*)d_ws;
    uint2* gr8  = (uint2*)ws;                                       // 51.2 MB
    float* part = (float*)(ws + (size_t)N_EDGE * 8);                // 400 KB
    char*  tail = ws + (size_t)N_EDGE * 8
                     + (size_t)N_STRUCT * NBLK_EL * sizeof(float);
    float4* pw4   = (float4*)tail;                                  // 2 KB
    float4* gw4   = (float4*)(tail + HID * 16);                     // 2 KB
    float*  sumw2 = (float*)(tail + 2 * HID * 16);

    hipLaunchKernelGGL(prep_kernel, dim3(1), dim3(128), 0, stream,
                       W1, w2, pw4, gw4, sumw2);
    hipLaunchKernelGGL(edge_local, dim3(NBLK_EL), dim3(256), 0, stream,
                       x, mask, bidx, pw4, gw4, sumw2, gr8, part);
    hipLaunchKernelGGL(atom_fused, dim3(NBLK_A), dim3(256), 0, stream,
                       gr8, nidx, npos, mask, part, out);
}